// Round 3
// baseline (761.683 us; speedup 1.0000x reference)
//
#include <hip/hip_runtime.h>
#include <hip/hip_bf16.h>

typedef __attribute__((ext_vector_type(4))) float f32x4;
typedef __attribute__((ext_vector_type(8))) short bf16x8;

#define BB 4
#define C 256
#define N 4096
#define EPSI 1e-5f

__device__ __forceinline__ unsigned short f2bf(float f) {
    unsigned int u = __builtin_bit_cast(unsigned int, f);
    u += 0x7fffu + ((u >> 16) & 1u);
    return (unsigned short)(u >> 16);
}

// ---------------- Kernel 1: BN stats -> scale/shift per channel ----------------
__global__ __launch_bounds__(256) void bn_stats_k(
    const float* __restrict__ x, const float* __restrict__ gamma,
    const float* __restrict__ beta, float* __restrict__ scale, float* __restrict__ shift)
{
    int c = blockIdx.x;
    int tid = threadIdx.x;
    float s = 0.f, s2 = 0.f;
    for (int b = 0; b < BB; ++b) {
        const float4* p = (const float4*)(x + ((size_t)b * C + c) * N);
        for (int i = tid; i < N / 4; i += 256) {
            float4 v = p[i];
            s  += v.x + v.y + v.z + v.w;
            s2 += v.x * v.x + v.y * v.y + v.z * v.z + v.w * v.w;
        }
    }
    for (int m = 1; m < 64; m <<= 1) {
        s  += __shfl_xor(s, m);
        s2 += __shfl_xor(s2, m);
    }
    __shared__ float rs[4], rs2[4];
    int w = tid >> 6;
    if ((tid & 63) == 0) { rs[w] = s; rs2[w] = s2; }
    __syncthreads();
    if (tid == 0) {
        float S  = rs[0] + rs[1] + rs[2] + rs[3];
        float S2 = rs2[0] + rs2[1] + rs2[2] + rs2[3];
        const float inv_n = 1.f / (BB * N);
        float mean = S * inv_n;
        float var  = S2 * inv_n - mean * mean;
        float sc = gamma[c] * rsqrtf(var + EPSI);
        scale[c] = sc;
        shift[c] = beta[c] - mean * sc;
    }
}

// ---------------- Kernel 2: fused BN-apply + QKV projection (bf16 MFMA) ----------------
__global__ __launch_bounds__(256) void qkv_gemm_k(
    const float* __restrict__ x, const float* __restrict__ Wqkv, const float* __restrict__ bqkv,
    const float* __restrict__ scale, const float* __restrict__ shift,
    unsigned short* __restrict__ q, unsigned short* __restrict__ kt, unsigned short* __restrict__ v)
{
    __shared__ unsigned short Alds[128 * 40];  // [t][c] transposed, padded 32->40
    __shared__ unsigned short Blds[64 * 40];   // [o][c]
    int tid = threadIdx.x;
    int b  = blockIdx.z;
    int T0 = blockIdx.y * 128;
    int O0 = blockIdx.x * 64;
    int lane = tid & 63;
    int w = tid >> 6;
    int wm = w >> 1, wn = w & 1;
    int g = lane >> 4, l15 = lane & 15;

    f32x4 acc[4][2];
    for (int i = 0; i < 4; ++i)
        for (int j = 0; j < 2; ++j) acc[i][j] = f32x4{0.f, 0.f, 0.f, 0.f};

    int a_c = tid >> 3;          // 0..31
    int a_t = (tid & 7) * 16;    // 0..112
    int b_o = tid >> 2;          // 0..63
    int b_c = (tid & 3) * 8;     // 0,8,16,24

    for (int c0 = 0; c0 < C; c0 += 32) {
        {
            int cg = c0 + a_c;
            const float4* xp = (const float4*)(x + ((size_t)b * C + cg) * N + T0 + a_t);
            float sc = scale[cg], sh = shift[cg];
            for (int j = 0; j < 4; ++j) {
                float4 vv = xp[j];
                int t = a_t + j * 4;
                Alds[(t + 0) * 40 + a_c] = f2bf(vv.x * sc + sh);
                Alds[(t + 1) * 40 + a_c] = f2bf(vv.y * sc + sh);
                Alds[(t + 2) * 40 + a_c] = f2bf(vv.z * sc + sh);
                Alds[(t + 3) * 40 + a_c] = f2bf(vv.w * sc + sh);
            }
        }
        {
            const float4* wp = (const float4*)(Wqkv + (size_t)(O0 + b_o) * C + c0 + b_c);
            float4 v0 = wp[0], v1 = wp[1];
            int base = b_o * 40 + b_c;
            Blds[base + 0] = f2bf(v0.x); Blds[base + 1] = f2bf(v0.y);
            Blds[base + 2] = f2bf(v0.z); Blds[base + 3] = f2bf(v0.w);
            Blds[base + 4] = f2bf(v1.x); Blds[base + 5] = f2bf(v1.y);
            Blds[base + 6] = f2bf(v1.z); Blds[base + 7] = f2bf(v1.w);
        }
        __syncthreads();
        bf16x8 bfr[2];
        for (int nf = 0; nf < 2; ++nf)
            bfr[nf] = *(const bf16x8*)&Blds[(wn * 32 + nf * 16 + l15) * 40 + g * 8];
        for (int mf = 0; mf < 4; ++mf) {
            bf16x8 afr = *(const bf16x8*)&Alds[(wm * 64 + mf * 16 + l15) * 40 + g * 8];
            for (int nf = 0; nf < 2; ++nf)
                acc[mf][nf] = __builtin_amdgcn_mfma_f32_16x16x32_bf16(afr, bfr[nf], acc[mf][nf], 0, 0, 0);
        }
        __syncthreads();
    }
    for (int mf = 0; mf < 4; ++mf) {
        for (int nf = 0; nf < 2; ++nf) {
            int o = O0 + wn * 32 + nf * 16 + l15;
            float bias = bqkv[o];
            for (int r = 0; r < 4; ++r) {
                int t = T0 + wm * 64 + mf * 16 + g * 4 + r;
                float val = acc[mf][nf][r] + bias;
                if (O0 < 256) {
                    q[((size_t)b * N + t) * C + o] = f2bf(val * 0.0625f);   // fold 1/sqrt(256)
                } else if (O0 < 512) {
                    kt[((size_t)b * N + t) * C + (o - 256)] = f2bf(val);
                } else {
                    v[((size_t)b * C + (o - 512)) * N + t] = f2bf(val);     // transposed store
                }
            }
        }
    }
}

// ---------------- Kernel 3: flash attention ----------------
// 8 waves/block, 1 block/CU, 2 waves/SIMD. Waves 0-3 handle KV[0,2048), waves 4-7
// KV[2048,4096), independent online softmax, combined at epilogue via LDS.
// T14 prefetch into registers; __launch_bounds__(512,2) keeps VGPR cap at 256 (no spill).
__global__ __launch_bounds__(512, 2) void attn_k(
    const unsigned short* __restrict__ q, const unsigned short* __restrict__ kt,
    const unsigned short* __restrict__ v, unsigned short* __restrict__ ao)
{
    __shared__ unsigned short Klds[2][64 * 256];   // per-group [tk][c], XOR-swizzled (64KB)
    __shared__ unsigned short Vlds[2][256 * 64];   // per-group [c][tk], XOR-swizzled (64KB)
    __shared__ unsigned short Plds[8][16 * 64];    // per-wave [qr][tk], XOR-swizzled (16KB)
    __shared__ float mlm[64], mll[64];

    int tid = threadIdx.x;
    int b  = blockIdx.y;
    int Q0 = blockIdx.x * 64;
    int lane = tid & 63;
    int w = tid >> 6;
    int lw = w & 3;        // wave's Q-row block
    int g2 = w >> 2;       // KV half
    int g = lane >> 4, l15 = lane & 15;
    int tg = tid & 255;    // thread index within group

    // Q fragments hoisted to registers
    bf16x8 qf[8];
    {
        const unsigned short* qp = q + ((size_t)b * N + Q0 + lw * 16 + l15) * C + g * 8;
        for (int kc = 0; kc < 8; ++kc)
            qf[kc] = *(const bf16x8*)(qp + kc * 32);
    }

    f32x4 oacc[16];
    for (int i = 0; i < 16; ++i) oacc[i] = f32x4{0.f, 0.f, 0.f, 0.f};
    float mrow[4], lrow[4];
    for (int r = 0; r < 4; ++r) { mrow[r] = -1e30f; lrow[r] = 0.f; }

    // staging decomposition (chunk = tg + j*256)
    int ktk = tg >> 5, kjj = tg & 31;   // K: row = ktk + j*8, col byte-group = kjj
    int vc0 = tg >> 3, vjj = tg & 7;    // V: c = vc0 + j*32, tk-group = vjj

    const unsigned short* kb = kt + ((size_t)b * N + g2 * 2048) * C;
    const unsigned short* vb = v + (size_t)b * C * N + g2 * 2048;

    bf16x8 kpre[8], vpre[8];
    // prologue: load tile 0
    for (int j = 0; j < 8; ++j)
        kpre[j] = *(const bf16x8*)(kb + (size_t)(ktk + j * 8) * C + kjj * 8);
    for (int j = 0; j < 8; ++j)
        vpre[j] = *(const bf16x8*)(vb + (size_t)(vc0 + j * 32) * N + vjj * 8);

    for (int it = 0; it < 32; ++it) {
        // write prefetched regs -> LDS (swizzled)
        for (int j = 0; j < 8; ++j) {
            int tk = ktk + j * 8;
            int idx = tk * 256 + kjj * 8;
            idx ^= (tk & 7) << 3;
            *(bf16x8*)&Klds[g2][idx] = kpre[j];
        }
        for (int j = 0; j < 8; ++j) {
            int c = vc0 + j * 32;
            int idx = c * 64 + vjj * 8;
            idx ^= (c & 7) << 3;
            *(bf16x8*)&Vlds[g2][idx] = vpre[j];
        }
        __syncthreads();

        // T14: issue next tile's global loads now; latency hides under compute
        int nit = (it < 31) ? it + 1 : 31;
        for (int j = 0; j < 8; ++j)
            kpre[j] = *(const bf16x8*)(kb + (size_t)(nit * 64 + ktk + j * 8) * C + kjj * 8);
        for (int j = 0; j < 8; ++j)
            vpre[j] = *(const bf16x8*)(vb + (size_t)(vc0 + j * 32) * N + nit * 64 + vjj * 8);

        // S = Q K^T
        f32x4 s[4];
        for (int ct = 0; ct < 4; ++ct) s[ct] = f32x4{0.f, 0.f, 0.f, 0.f};
        for (int kc = 0; kc < 8; ++kc) {
            for (int ct = 0; ct < 4; ++ct) {
                int tk = ct * 16 + l15;
                int idx = tk * 256 + kc * 32 + g * 8;
                idx ^= (tk & 7) << 3;
                bf16x8 kf = *(const bf16x8*)&Klds[g2][idx];
                s[ct] = __builtin_amdgcn_mfma_f32_16x16x32_bf16(qf[kc], kf, s[ct], 0, 0, 0);
            }
        }

        // online softmax (all 64 lanes active)
        float alpha[4];
        for (int r = 0; r < 4; ++r) {
            float mx = fmaxf(fmaxf(s[0][r], s[1][r]), fmaxf(s[2][r], s[3][r]));
            for (int off = 1; off < 16; off <<= 1) mx = fmaxf(mx, __shfl_xor(mx, off));
            float mn = fmaxf(mrow[r], mx);
            alpha[r] = __expf(mrow[r] - mn);
            mrow[r] = mn;
            float rs = 0.f;
            for (int ct = 0; ct < 4; ++ct) {
                float p = __expf(s[ct][r] - mn);
                s[ct][r] = p;
                rs += p;
            }
            for (int off = 1; off < 16; off <<= 1) rs += __shfl_xor(rs, off);
            lrow[r] = lrow[r] * alpha[r] + rs;
        }
        // exact skip: if no row's max moved, alpha==1 and rescale is a no-op
        bool nochg = (alpha[0] == 1.f) & (alpha[1] == 1.f) & (alpha[2] == 1.f) & (alpha[3] == 1.f);
        if (!__all(nochg)) {
            for (int f = 0; f < 16; ++f)
                for (int r = 0; r < 4; ++r) oacc[f][r] *= alpha[r];
        }

        // P -> per-wave LDS (bf16, swizzled)
        for (int ct = 0; ct < 4; ++ct) {
            for (int r = 0; r < 4; ++r) {
                int row = g * 4 + r;
                int idx = row * 64 + ct * 16 + l15;
                idx ^= (row & 7) << 3;
                Plds[w][idx] = f2bf(s[ct][r]);
            }
        }

        // O += P V
        for (int ks = 0; ks < 2; ++ks) {
            int pidx = l15 * 64 + ks * 32 + g * 8;
            pidx ^= (l15 & 7) << 3;
            bf16x8 pf = *(const bf16x8*)&Plds[w][pidx];
            for (int cf = 0; cf < 16; ++cf) {
                int c = cf * 16 + l15;
                int vidx = c * 64 + ks * 32 + g * 8;
                vidx ^= (c & 7) << 3;
                bf16x8 vf = *(const bf16x8*)&Vlds[g2][vidx];
                oacc[cf] = __builtin_amdgcn_mfma_f32_16x16x32_bf16(pf, vf, oacc[cf], 0, 0, 0);
            }
        }
        __syncthreads();
    }

    // ---- epilogue: combine the two KV halves via LDS (reuse Klds as fp32 buffer) ----
    float* Ocomb = (float*)&Klds[0][0];   // 64 rows x 256 c fp32 = 64KB
    if (g2 == 1) {
        for (int cf = 0; cf < 16; ++cf)
            for (int r = 0; r < 4; ++r)
                Ocomb[(size_t)(lw * 16 + g * 4 + r) * 256 + cf * 16 + l15] = oacc[cf][r];
        if (l15 == 0) {
            for (int r = 0; r < 4; ++r) {
                int row = lw * 16 + g * 4 + r;
                mlm[row] = mrow[r];
                mll[row] = lrow[r];
            }
        }
    }
    __syncthreads();
    if (g2 == 0) {
        float w0[4], w1[4];
        for (int r = 0; r < 4; ++r) {
            int row = lw * 16 + g * 4 + r;
            float m1 = mlm[row], l1 = mll[row];
            float m = fmaxf(mrow[r], m1);
            float a0 = __expf(mrow[r] - m), a1 = __expf(m1 - m);
            float inv = 1.f / (a0 * lrow[r] + a1 * l1);
            w0[r] = a0 * inv;
            w1[r] = a1 * inv;
        }
        for (int cf = 0; cf < 16; ++cf) {
            int c = cf * 16 + l15;
            for (int r = 0; r < 4; ++r) {
                int row = lw * 16 + g * 4 + r;
                float val = w0[r] * oacc[cf][r] + w1[r] * Ocomb[(size_t)row * 256 + c];
                ao[((size_t)b * N + Q0 + row) * C + c] = f2bf(val);
            }
        }
    }
}

// ---------------- Kernel 4: out projection + bias + residual ----------------
__global__ __launch_bounds__(256) void out_gemm_k(
    const unsigned short* __restrict__ ao, const float* __restrict__ Wout,
    const float* __restrict__ bout, const float* __restrict__ x, float* __restrict__ out)
{
    __shared__ unsigned short Alds[64 * 72];
    __shared__ unsigned short Blds[128 * 72];
    int tid = threadIdx.x;
    int b   = blockIdx.z;
    int CO0 = blockIdx.y * 64;
    int T0  = blockIdx.x * 128;
    int lane = tid & 63;
    int w = tid >> 6;
    int wm = w >> 1, wn = w & 1;
    int g = lane >> 4, l15 = lane & 15;

    f32x4 acc[2][4];
    for (int i = 0; i < 2; ++i)
        for (int j = 0; j < 4; ++j) acc[i][j] = f32x4{0.f, 0.f, 0.f, 0.f};

    int a_r = tid >> 2;
    int a_cb = (tid & 3) * 16;

    for (int c0 = 0; c0 < C; c0 += 64) {
        {
            const float4* wp = (const float4*)(Wout + (size_t)(CO0 + a_r) * C + c0 + a_cb);
            for (int j = 0; j < 4; ++j) {
                float4 vv = wp[j];
                int base = a_r * 72 + a_cb + j * 4;
                Alds[base + 0] = f2bf(vv.x);
                Alds[base + 1] = f2bf(vv.y);
                Alds[base + 2] = f2bf(vv.z);
                Alds[base + 3] = f2bf(vv.w);
            }
        }
        for (int it = 0; it < 4; ++it) {
            int chunk = tid + it * 256;
            int tl = chunk >> 3, j = chunk & 7;
            *(bf16x8*)&Blds[tl * 72 + j * 8] =
                *(const bf16x8*)(ao + ((size_t)b * N + T0 + tl) * C + c0 + j * 8);
        }
        __syncthreads();
        for (int kk = 0; kk < 2; ++kk) {
            bf16x8 bfr[4];
            for (int nf = 0; nf < 4; ++nf)
                bfr[nf] = *(const bf16x8*)&Blds[(wn * 64 + nf * 16 + l15) * 72 + kk * 32 + g * 8];
            for (int mf = 0; mf < 2; ++mf) {
                bf16x8 afr = *(const bf16x8*)&Alds[(wm * 32 + mf * 16 + l15) * 72 + kk * 32 + g * 8];
                for (int nf = 0; nf < 4; ++nf)
                    acc[mf][nf] = __builtin_amdgcn_mfma_f32_16x16x32_bf16(afr, bfr[nf], acc[mf][nf], 0, 0, 0);
            }
        }
        __syncthreads();
    }
    for (int mf = 0; mf < 2; ++mf) {
        for (int nf = 0; nf < 4; ++nf) {
            int t = T0 + wn * 64 + nf * 16 + l15;
            for (int r = 0; r < 4; ++r) {
                int co = CO0 + wm * 32 + mf * 16 + g * 4 + r;
                size_t oidx = ((size_t)b * C + co) * N + t;
                out[oidx] = acc[mf][nf][r] + bout[co] + x[oidx];
            }
        }
    }
}

extern "C" void kernel_launch(void* const* d_in, const int* in_sizes, int n_in,
                              void* d_out, int out_size, void* d_ws, size_t ws_size,
                              hipStream_t stream) {
    const float* x     = (const float*)d_in[0];
    const float* Wqkv  = (const float*)d_in[1];
    const float* bqkv  = (const float*)d_in[2];
    const float* Wout  = (const float*)d_in[3];
    const float* bout  = (const float*)d_in[4];
    const float* gamma = (const float*)d_in[5];
    const float* beta  = (const float*)d_in[6];
    float* out = (float*)d_out;

    char* ws = (char*)d_ws;
    float* scale = (float*)ws;
    float* shift = (float*)(ws + 1024);
    unsigned short* q  = (unsigned short*)(ws + 4096);
    unsigned short* kt = q  + (size_t)BB * N * C;
    unsigned short* v  = kt + (size_t)BB * N * C;
    unsigned short* ao = v  + (size_t)BB * N * C;

    bn_stats_k<<<dim3(C), dim3(256), 0, stream>>>(x, gamma, beta, scale, shift);
    qkv_gemm_k<<<dim3(12, 32, BB), dim3(256), 0, stream>>>(x, Wqkv, bqkv, scale, shift, q, kt, v);
    attn_k<<<dim3(64, BB), dim3(512), 0, stream>>>(q, kt, v, ao);
    out_gemm_k<<<dim3(32, 4, BB), dim3(256), 0, stream>>>(ao, Wout, bout, x, out);
}

// Round 4
// 761.140 us; speedup vs baseline: 1.0007x; 1.0007x over previous
//
#include <hip/hip_runtime.h>
#include <hip/hip_bf16.h>

typedef __attribute__((ext_vector_type(4))) float f32x4;
typedef __attribute__((ext_vector_type(8))) short bf16x8;

#define BB 4
#define C 256
#define N 4096
#define EPSI 1e-5f

__device__ __forceinline__ unsigned short f2bf(float f) {
    unsigned int u = __builtin_bit_cast(unsigned int, f);
    u += 0x7fffu + ((u >> 16) & 1u);
    return (unsigned short)(u >> 16);
}

// ---------------- Kernel 1: BN stats -> scale/shift per channel ----------------
__global__ __launch_bounds__(256) void bn_stats_k(
    const float* __restrict__ x, const float* __restrict__ gamma,
    const float* __restrict__ beta, float* __restrict__ scale, float* __restrict__ shift)
{
    int c = blockIdx.x;
    int tid = threadIdx.x;
    float s = 0.f, s2 = 0.f;
    for (int b = 0; b < BB; ++b) {
        const float4* p = (const float4*)(x + ((size_t)b * C + c) * N);
        for (int i = tid; i < N / 4; i += 256) {
            float4 v = p[i];
            s  += v.x + v.y + v.z + v.w;
            s2 += v.x * v.x + v.y * v.y + v.z * v.z + v.w * v.w;
        }
    }
    for (int m = 1; m < 64; m <<= 1) {
        s  += __shfl_xor(s, m);
        s2 += __shfl_xor(s2, m);
    }
    __shared__ float rs[4], rs2[4];
    int w = tid >> 6;
    if ((tid & 63) == 0) { rs[w] = s; rs2[w] = s2; }
    __syncthreads();
    if (tid == 0) {
        float S  = rs[0] + rs[1] + rs[2] + rs[3];
        float S2 = rs2[0] + rs2[1] + rs2[2] + rs2[3];
        const float inv_n = 1.f / (BB * N);
        float mean = S * inv_n;
        float var  = S2 * inv_n - mean * mean;
        float sc = gamma[c] * rsqrtf(var + EPSI);
        scale[c] = sc;
        shift[c] = beta[c] - mean * sc;
    }
}

// ---------------- Kernel 2: fused BN-apply + QKV projection (bf16 MFMA) ----------------
__global__ __launch_bounds__(256) void qkv_gemm_k(
    const float* __restrict__ x, const float* __restrict__ Wqkv, const float* __restrict__ bqkv,
    const float* __restrict__ scale, const float* __restrict__ shift,
    unsigned short* __restrict__ q, unsigned short* __restrict__ kt, unsigned short* __restrict__ v)
{
    __shared__ unsigned short Alds[128 * 40];  // [t][c] transposed, padded 32->40
    __shared__ unsigned short Blds[64 * 40];   // [o][c]
    int tid = threadIdx.x;
    int b  = blockIdx.z;
    int T0 = blockIdx.y * 128;
    int O0 = blockIdx.x * 64;
    int lane = tid & 63;
    int w = tid >> 6;
    int wm = w >> 1, wn = w & 1;
    int g = lane >> 4, l15 = lane & 15;

    f32x4 acc[4][2];
    for (int i = 0; i < 4; ++i)
        for (int j = 0; j < 2; ++j) acc[i][j] = f32x4{0.f, 0.f, 0.f, 0.f};

    int a_c = tid >> 3;          // 0..31
    int a_t = (tid & 7) * 16;    // 0..112
    int b_o = tid >> 2;          // 0..63
    int b_c = (tid & 3) * 8;     // 0,8,16,24

    for (int c0 = 0; c0 < C; c0 += 32) {
        {
            int cg = c0 + a_c;
            const float4* xp = (const float4*)(x + ((size_t)b * C + cg) * N + T0 + a_t);
            float sc = scale[cg], sh = shift[cg];
            for (int j = 0; j < 4; ++j) {
                float4 vv = xp[j];
                int t = a_t + j * 4;
                Alds[(t + 0) * 40 + a_c] = f2bf(vv.x * sc + sh);
                Alds[(t + 1) * 40 + a_c] = f2bf(vv.y * sc + sh);
                Alds[(t + 2) * 40 + a_c] = f2bf(vv.z * sc + sh);
                Alds[(t + 3) * 40 + a_c] = f2bf(vv.w * sc + sh);
            }
        }
        {
            const float4* wp = (const float4*)(Wqkv + (size_t)(O0 + b_o) * C + c0 + b_c);
            float4 v0 = wp[0], v1 = wp[1];
            int base = b_o * 40 + b_c;
            Blds[base + 0] = f2bf(v0.x); Blds[base + 1] = f2bf(v0.y);
            Blds[base + 2] = f2bf(v0.z); Blds[base + 3] = f2bf(v0.w);
            Blds[base + 4] = f2bf(v1.x); Blds[base + 5] = f2bf(v1.y);
            Blds[base + 6] = f2bf(v1.z); Blds[base + 7] = f2bf(v1.w);
        }
        __syncthreads();
        bf16x8 bfr[2];
        for (int nf = 0; nf < 2; ++nf)
            bfr[nf] = *(const bf16x8*)&Blds[(wn * 32 + nf * 16 + l15) * 40 + g * 8];
        for (int mf = 0; mf < 4; ++mf) {
            bf16x8 afr = *(const bf16x8*)&Alds[(wm * 64 + mf * 16 + l15) * 40 + g * 8];
            for (int nf = 0; nf < 2; ++nf)
                acc[mf][nf] = __builtin_amdgcn_mfma_f32_16x16x32_bf16(afr, bfr[nf], acc[mf][nf], 0, 0, 0);
        }
        __syncthreads();
    }
    for (int mf = 0; mf < 4; ++mf) {
        for (int nf = 0; nf < 2; ++nf) {
            int o = O0 + wn * 32 + nf * 16 + l15;
            float bias = bqkv[o];
            for (int r = 0; r < 4; ++r) {
                int t = T0 + wm * 64 + mf * 16 + g * 4 + r;
                float val = acc[mf][nf][r] + bias;
                if (O0 < 256) {
                    q[((size_t)b * N + t) * C + o] = f2bf(val * 0.0625f);   // fold 1/sqrt(256)
                } else if (O0 < 512) {
                    kt[((size_t)b * N + t) * C + (o - 256)] = f2bf(val);
                } else {
                    v[((size_t)b * C + (o - 512)) * N + t] = f2bf(val);     // transposed store
                }
            }
        }
    }
}

// ---------------- Kernel 3: flash attention ----------------
// 8 waves/block, 1 block/CU, 2 waves/SIMD. Waves 0-3 handle KV[0,2048), waves 4-7
// KV[2048,4096), independent online softmax, combined at epilogue via LDS.
// __launch_bounds__(512, 1): min 1 block/CU -> VGPR cap 256 (8-wave workgroup forces
// <=256 anyway); prevents the 128-cap spill seen with (512,2) [VGPR=128, FETCH=630MB].
__global__ __launch_bounds__(512, 1) void attn_k(
    const unsigned short* __restrict__ q, const unsigned short* __restrict__ kt,
    const unsigned short* __restrict__ v, unsigned short* __restrict__ ao)
{
    __shared__ unsigned short Klds[2][64 * 256];   // per-group [tk][c], XOR-swizzled (64KB)
    __shared__ unsigned short Vlds[2][256 * 64];   // per-group [c][tk], XOR-swizzled (64KB)
    __shared__ unsigned short Plds[8][16 * 64];    // per-wave [qr][tk], XOR-swizzled (16KB)
    __shared__ float mlm[64], mll[64];

    int tid = threadIdx.x;
    int b  = blockIdx.y;
    int Q0 = blockIdx.x * 64;
    int lane = tid & 63;
    int w = tid >> 6;
    int lw = w & 3;        // wave's Q-row block
    int g2 = w >> 2;       // KV half
    int g = lane >> 4, l15 = lane & 15;
    int tg = tid & 255;    // thread index within group

    // Q fragments hoisted to registers
    bf16x8 qf[8];
    {
        const unsigned short* qp = q + ((size_t)b * N + Q0 + lw * 16 + l15) * C + g * 8;
#pragma unroll
        for (int kc = 0; kc < 8; ++kc)
            qf[kc] = *(const bf16x8*)(qp + kc * 32);
    }

    f32x4 oacc[16];
#pragma unroll
    for (int i = 0; i < 16; ++i) oacc[i] = f32x4{0.f, 0.f, 0.f, 0.f};
    float mrow[4], lrow[4];
#pragma unroll
    for (int r = 0; r < 4; ++r) { mrow[r] = -1e30f; lrow[r] = 0.f; }

    // staging decomposition (chunk = tg + j*256)
    int ktk = tg >> 5, kjj = tg & 31;   // K: row = ktk + j*8, col byte-group = kjj
    int vc0 = tg >> 3, vjj = tg & 7;    // V: c = vc0 + j*32, tk-group = vjj

    const unsigned short* kb = kt + ((size_t)b * N + g2 * 2048) * C;
    const unsigned short* vb = v + (size_t)b * C * N + g2 * 2048;

    bf16x8 kpre[8], vpre[8];
    // prologue: load tile 0
#pragma unroll
    for (int j = 0; j < 8; ++j)
        kpre[j] = *(const bf16x8*)(kb + (size_t)(ktk + j * 8) * C + kjj * 8);
#pragma unroll
    for (int j = 0; j < 8; ++j)
        vpre[j] = *(const bf16x8*)(vb + (size_t)(vc0 + j * 32) * N + vjj * 8);

    for (int it = 0; it < 32; ++it) {
        // write prefetched regs -> LDS (swizzled)
#pragma unroll
        for (int j = 0; j < 8; ++j) {
            int tk = ktk + j * 8;
            int idx = tk * 256 + kjj * 8;
            idx ^= (tk & 7) << 3;
            *(bf16x8*)&Klds[g2][idx] = kpre[j];
        }
#pragma unroll
        for (int j = 0; j < 8; ++j) {
            int c = vc0 + j * 32;
            int idx = c * 64 + vjj * 8;
            idx ^= (c & 7) << 3;
            *(bf16x8*)&Vlds[g2][idx] = vpre[j];
        }
        __syncthreads();

        // T14: issue next tile's global loads now; latency hides under compute
        int nit = (it < 31) ? it + 1 : 31;
#pragma unroll
        for (int j = 0; j < 8; ++j)
            kpre[j] = *(const bf16x8*)(kb + (size_t)(nit * 64 + ktk + j * 8) * C + kjj * 8);
#pragma unroll
        for (int j = 0; j < 8; ++j)
            vpre[j] = *(const bf16x8*)(vb + (size_t)(vc0 + j * 32) * N + nit * 64 + vjj * 8);

        // S = Q K^T
        f32x4 s[4];
#pragma unroll
        for (int ct = 0; ct < 4; ++ct) s[ct] = f32x4{0.f, 0.f, 0.f, 0.f};
#pragma unroll
        for (int kc = 0; kc < 8; ++kc) {
#pragma unroll
            for (int ct = 0; ct < 4; ++ct) {
                int tk = ct * 16 + l15;
                int idx = tk * 256 + kc * 32 + g * 8;
                idx ^= (tk & 7) << 3;
                bf16x8 kf = *(const bf16x8*)&Klds[g2][idx];
                s[ct] = __builtin_amdgcn_mfma_f32_16x16x32_bf16(qf[kc], kf, s[ct], 0, 0, 0);
            }
        }

        // online softmax (all 64 lanes active)
        float alpha[4];
#pragma unroll
        for (int r = 0; r < 4; ++r) {
            float mx = fmaxf(fmaxf(s[0][r], s[1][r]), fmaxf(s[2][r], s[3][r]));
            for (int off = 1; off < 16; off <<= 1) mx = fmaxf(mx, __shfl_xor(mx, off));
            float mn = fmaxf(mrow[r], mx);
            alpha[r] = __expf(mrow[r] - mn);
            mrow[r] = mn;
            float rs = 0.f;
#pragma unroll
            for (int ct = 0; ct < 4; ++ct) {
                float p = __expf(s[ct][r] - mn);
                s[ct][r] = p;
                rs += p;
            }
            for (int off = 1; off < 16; off <<= 1) rs += __shfl_xor(rs, off);
            lrow[r] = lrow[r] * alpha[r] + rs;
        }
        // exact skip: if no row's max moved, alpha==1 and rescale is a no-op
        bool nochg = (alpha[0] == 1.f) & (alpha[1] == 1.f) & (alpha[2] == 1.f) & (alpha[3] == 1.f);
        if (!__all(nochg)) {
#pragma unroll
            for (int f = 0; f < 16; ++f)
#pragma unroll
                for (int r = 0; r < 4; ++r) oacc[f][r] *= alpha[r];
        }

        // P -> per-wave LDS (bf16, swizzled)
#pragma unroll
        for (int ct = 0; ct < 4; ++ct) {
#pragma unroll
            for (int r = 0; r < 4; ++r) {
                int row = g * 4 + r;
                int idx = row * 64 + ct * 16 + l15;
                idx ^= (row & 7) << 3;
                Plds[w][idx] = f2bf(s[ct][r]);
            }
        }

        // O += P V
#pragma unroll
        for (int ks = 0; ks < 2; ++ks) {
            int pidx = l15 * 64 + ks * 32 + g * 8;
            pidx ^= (l15 & 7) << 3;
            bf16x8 pf = *(const bf16x8*)&Plds[w][pidx];
#pragma unroll
            for (int cf = 0; cf < 16; ++cf) {
                int c = cf * 16 + l15;
                int vidx = c * 64 + ks * 32 + g * 8;
                vidx ^= (c & 7) << 3;
                bf16x8 vf = *(const bf16x8*)&Vlds[g2][vidx];
                oacc[cf] = __builtin_amdgcn_mfma_f32_16x16x32_bf16(pf, vf, oacc[cf], 0, 0, 0);
            }
        }
        __syncthreads();
    }

    // ---- epilogue: combine the two KV halves via LDS (reuse Klds as fp32 buffer) ----
    float* Ocomb = (float*)&Klds[0][0];   // 64 rows x 256 c fp32 = 64KB
    if (g2 == 1) {
#pragma unroll
        for (int cf = 0; cf < 16; ++cf)
#pragma unroll
            for (int r = 0; r < 4; ++r)
                Ocomb[(size_t)(lw * 16 + g * 4 + r) * 256 + cf * 16 + l15] = oacc[cf][r];
        if (l15 == 0) {
#pragma unroll
            for (int r = 0; r < 4; ++r) {
                int row = lw * 16 + g * 4 + r;
                mlm[row] = mrow[r];
                mll[row] = lrow[r];
            }
        }
    }
    __syncthreads();
    if (g2 == 0) {
        float w0[4], w1[4];
#pragma unroll
        for (int r = 0; r < 4; ++r) {
            int row = lw * 16 + g * 4 + r;
            float m1 = mlm[row], l1 = mll[row];
            float m = fmaxf(mrow[r], m1);
            float a0 = __expf(mrow[r] - m), a1 = __expf(m1 - m);
            float inv = 1.f / (a0 * lrow[r] + a1 * l1);
            w0[r] = a0 * inv;
            w1[r] = a1 * inv;
        }
#pragma unroll
        for (int cf = 0; cf < 16; ++cf) {
            int c = cf * 16 + l15;
#pragma unroll
            for (int r = 0; r < 4; ++r) {
                int row = lw * 16 + g * 4 + r;
                float val = w0[r] * oacc[cf][r] + w1[r] * Ocomb[(size_t)row * 256 + c];
                ao[((size_t)b * N + Q0 + row) * C + c] = f2bf(val);
            }
        }
    }
}

// ---------------- Kernel 4: out projection + bias + residual ----------------
__global__ __launch_bounds__(256) void out_gemm_k(
    const unsigned short* __restrict__ ao, const float* __restrict__ Wout,
    const float* __restrict__ bout, const float* __restrict__ x, float* __restrict__ out)
{
    __shared__ unsigned short Alds[64 * 72];
    __shared__ unsigned short Blds[128 * 72];
    int tid = threadIdx.x;
    int b   = blockIdx.z;
    int CO0 = blockIdx.y * 64;
    int T0  = blockIdx.x * 128;
    int lane = tid & 63;
    int w = tid >> 6;
    int wm = w >> 1, wn = w & 1;
    int g = lane >> 4, l15 = lane & 15;

    f32x4 acc[2][4];
    for (int i = 0; i < 2; ++i)
        for (int j = 0; j < 4; ++j) acc[i][j] = f32x4{0.f, 0.f, 0.f, 0.f};

    int a_r = tid >> 2;
    int a_cb = (tid & 3) * 16;

    for (int c0 = 0; c0 < C; c0 += 64) {
        {
            const float4* wp = (const float4*)(Wout + (size_t)(CO0 + a_r) * C + c0 + a_cb);
            for (int j = 0; j < 4; ++j) {
                float4 vv = wp[j];
                int base = a_r * 72 + a_cb + j * 4;
                Alds[base + 0] = f2bf(vv.x);
                Alds[base + 1] = f2bf(vv.y);
                Alds[base + 2] = f2bf(vv.z);
                Alds[base + 3] = f2bf(vv.w);
            }
        }
        for (int it = 0; it < 4; ++it) {
            int chunk = tid + it * 256;
            int tl = chunk >> 3, j = chunk & 7;
            *(bf16x8*)&Blds[tl * 72 + j * 8] =
                *(const bf16x8*)(ao + ((size_t)b * N + T0 + tl) * C + c0 + j * 8);
        }
        __syncthreads();
        for (int kk = 0; kk < 2; ++kk) {
            bf16x8 bfr[4];
            for (int nf = 0; nf < 4; ++nf)
                bfr[nf] = *(const bf16x8*)&Blds[(wn * 64 + nf * 16 + l15) * 72 + kk * 32 + g * 8];
            for (int mf = 0; mf < 2; ++mf) {
                bf16x8 afr = *(const bf16x8*)&Alds[(wm * 32 + mf * 16 + l15) * 72 + kk * 32 + g * 8];
                for (int nf = 0; nf < 4; ++nf)
                    acc[mf][nf] = __builtin_amdgcn_mfma_f32_16x16x32_bf16(afr, bfr[nf], acc[mf][nf], 0, 0, 0);
            }
        }
        __syncthreads();
    }
    for (int mf = 0; mf < 2; ++mf) {
        for (int nf = 0; nf < 4; ++nf) {
            int t = T0 + wn * 64 + nf * 16 + l15;
            for (int r = 0; r < 4; ++r) {
                int co = CO0 + wm * 32 + mf * 16 + g * 4 + r;
                size_t oidx = ((size_t)b * C + co) * N + t;
                out[oidx] = acc[mf][nf][r] + bout[co] + x[oidx];
            }
        }
    }
}

extern "C" void kernel_launch(void* const* d_in, const int* in_sizes, int n_in,
                              void* d_out, int out_size, void* d_ws, size_t ws_size,
                              hipStream_t stream) {
    const float* x     = (const float*)d_in[0];
    const float* Wqkv  = (const float*)d_in[1];
    const float* bqkv  = (const float*)d_in[2];
    const float* Wout  = (const float*)d_in[3];
    const float* bout  = (const float*)d_in[4];
    const float* gamma = (const float*)d_in[5];
    const float* beta  = (const float*)d_in[6];
    float* out = (float*)d_out;

    char* ws = (char*)d_ws;
    float* scale = (float*)ws;
    float* shift = (float*)(ws + 1024);
    unsigned short* q  = (unsigned short*)(ws + 4096);
    unsigned short* kt = q  + (size_t)BB * N * C;
    unsigned short* v  = kt + (size_t)BB * N * C;
    unsigned short* ao = v  + (size_t)BB * N * C;

    bn_stats_k<<<dim3(C), dim3(256), 0, stream>>>(x, gamma, beta, scale, shift);
    qkv_gemm_k<<<dim3(12, 32, BB), dim3(256), 0, stream>>>(x, Wqkv, bqkv, scale, shift, q, kt, v);
    attn_k<<<dim3(64, BB), dim3(512), 0, stream>>>(q, kt, v, ao);
    out_gemm_k<<<dim3(32, 4, BB), dim3(256), 0, stream>>>(ao, Wout, bout, x, out);
}

// Round 5
// 239.738 us; speedup vs baseline: 3.1771x; 3.1749x over previous
//
#include <hip/hip_runtime.h>
#include <hip/hip_bf16.h>

typedef __attribute__((ext_vector_type(4))) float f32x4;
typedef __attribute__((ext_vector_type(8))) short bf16x8;

#define BB 4
#define C 256
#define N 4096
#define TS 32
#define EPSI 1e-5f

__device__ __forceinline__ unsigned short f2bf(float f) {
    unsigned int u = __builtin_bit_cast(unsigned int, f);
    u += 0x7fffu + ((u >> 16) & 1u);
    return (unsigned short)(u >> 16);
}

// async global->LDS, 16B per lane; LDS dest must be uniform-base + lane*16 (it is).
__device__ __forceinline__ void stage16(const unsigned short* g, unsigned short* l) {
    __builtin_amdgcn_global_load_lds(
        (const __attribute__((address_space(1))) void*)g,
        (__attribute__((address_space(3))) void*)l, 16, 0, 0);
}

// ---------------- Kernel 1: BN stats -> scale/shift per channel ----------------
__global__ __launch_bounds__(256) void bn_stats_k(
    const float* __restrict__ x, const float* __restrict__ gamma,
    const float* __restrict__ beta, float* __restrict__ scale, float* __restrict__ shift)
{
    int c = blockIdx.x;
    int tid = threadIdx.x;
    float s = 0.f, s2 = 0.f;
    for (int b = 0; b < BB; ++b) {
        const float4* p = (const float4*)(x + ((size_t)b * C + c) * N);
        for (int i = tid; i < N / 4; i += 256) {
            float4 v = p[i];
            s  += v.x + v.y + v.z + v.w;
            s2 += v.x * v.x + v.y * v.y + v.z * v.z + v.w * v.w;
        }
    }
    for (int m = 1; m < 64; m <<= 1) {
        s  += __shfl_xor(s, m);
        s2 += __shfl_xor(s2, m);
    }
    __shared__ float rs[4], rs2[4];
    int w = tid >> 6;
    if ((tid & 63) == 0) { rs[w] = s; rs2[w] = s2; }
    __syncthreads();
    if (tid == 0) {
        float S  = rs[0] + rs[1] + rs[2] + rs[3];
        float S2 = rs2[0] + rs2[1] + rs2[2] + rs2[3];
        const float inv_n = 1.f / (BB * N);
        float mean = S * inv_n;
        float var  = S2 * inv_n - mean * mean;
        float sc = gamma[c] * rsqrtf(var + EPSI);
        scale[c] = sc;
        shift[c] = beta[c] - mean * sc;
    }
}

// ---------------- Kernel 2: fused BN-apply + QKV projection (bf16 MFMA) ----------------
__global__ __launch_bounds__(256) void qkv_gemm_k(
    const float* __restrict__ x, const float* __restrict__ Wqkv, const float* __restrict__ bqkv,
    const float* __restrict__ scale, const float* __restrict__ shift,
    unsigned short* __restrict__ q, unsigned short* __restrict__ kt, unsigned short* __restrict__ v)
{
    __shared__ unsigned short Alds[128 * 40];  // [t][c] transposed, padded 32->40
    __shared__ unsigned short Blds[64 * 40];   // [o][c]
    int tid = threadIdx.x;
    int b  = blockIdx.z;
    int T0 = blockIdx.y * 128;
    int O0 = blockIdx.x * 64;
    int lane = tid & 63;
    int w = tid >> 6;
    int wm = w >> 1, wn = w & 1;
    int g = lane >> 4, l15 = lane & 15;

    f32x4 acc[4][2];
    for (int i = 0; i < 4; ++i)
        for (int j = 0; j < 2; ++j) acc[i][j] = f32x4{0.f, 0.f, 0.f, 0.f};

    int a_c = tid >> 3;          // 0..31
    int a_t = (tid & 7) * 16;    // 0..112
    int b_o = tid >> 2;          // 0..63
    int b_c = (tid & 3) * 8;     // 0,8,16,24

    for (int c0 = 0; c0 < C; c0 += 32) {
        {
            int cg = c0 + a_c;
            const float4* xp = (const float4*)(x + ((size_t)b * C + cg) * N + T0 + a_t);
            float sc = scale[cg], sh = shift[cg];
            for (int j = 0; j < 4; ++j) {
                float4 vv = xp[j];
                int t = a_t + j * 4;
                Alds[(t + 0) * 40 + a_c] = f2bf(vv.x * sc + sh);
                Alds[(t + 1) * 40 + a_c] = f2bf(vv.y * sc + sh);
                Alds[(t + 2) * 40 + a_c] = f2bf(vv.z * sc + sh);
                Alds[(t + 3) * 40 + a_c] = f2bf(vv.w * sc + sh);
            }
        }
        {
            const float4* wp = (const float4*)(Wqkv + (size_t)(O0 + b_o) * C + c0 + b_c);
            float4 v0 = wp[0], v1 = wp[1];
            int base = b_o * 40 + b_c;
            Blds[base + 0] = f2bf(v0.x); Blds[base + 1] = f2bf(v0.y);
            Blds[base + 2] = f2bf(v0.z); Blds[base + 3] = f2bf(v0.w);
            Blds[base + 4] = f2bf(v1.x); Blds[base + 5] = f2bf(v1.y);
            Blds[base + 6] = f2bf(v1.z); Blds[base + 7] = f2bf(v1.w);
        }
        __syncthreads();
        bf16x8 bfr[2];
        for (int nf = 0; nf < 2; ++nf)
            bfr[nf] = *(const bf16x8*)&Blds[(wn * 32 + nf * 16 + l15) * 40 + g * 8];
        for (int mf = 0; mf < 4; ++mf) {
            bf16x8 afr = *(const bf16x8*)&Alds[(wm * 64 + mf * 16 + l15) * 40 + g * 8];
            for (int nf = 0; nf < 2; ++nf)
                acc[mf][nf] = __builtin_amdgcn_mfma_f32_16x16x32_bf16(afr, bfr[nf], acc[mf][nf], 0, 0, 0);
        }
        __syncthreads();
    }
    for (int mf = 0; mf < 4; ++mf) {
        for (int nf = 0; nf < 2; ++nf) {
            int o = O0 + wn * 32 + nf * 16 + l15;
            float bias = bqkv[o];
            for (int r = 0; r < 4; ++r) {
                int t = T0 + wm * 64 + mf * 16 + g * 4 + r;
                float val = acc[mf][nf][r] + bias;
                if (O0 < 256) {
                    q[((size_t)b * N + t) * C + o] = f2bf(val * 0.0625f);   // fold 1/sqrt(256)
                } else if (O0 < 512) {
                    kt[((size_t)b * N + t) * C + (o - 256)] = f2bf(val);
                } else {
                    v[((size_t)b * C + (o - 512)) * N + t] = f2bf(val);     // transposed store
                }
            }
        }
    }
}

// ---------------- Kernel 3: flash attention ----------------
// 8 waves (512 thr), waves 0-3: KV[0,2048), waves 4-7: KV[2048,4096); independent
// online softmax combined at epilogue via LDS. KV tiles of 32 double-buffered,
// staged via global_load_lds (width 16) -> no staging VGPRs -> nothing to spill
// under the 128-VGPR cap. Swizzle is both-sides: linear LDS dest, inverse-XOR'd
// per-lane GLOBAL source, same XOR on ds_read (rule 21).
__global__ __launch_bounds__(512) void attn_k(
    const unsigned short* __restrict__ q, const unsigned short* __restrict__ kt,
    const unsigned short* __restrict__ v, unsigned short* __restrict__ ao)
{
    __shared__ unsigned short Klds[2][2][TS * 256];   // [grp][buf][tk][c-chunks^] 64KB
    __shared__ unsigned short Vlds[2][2][256 * TS];   // [grp][buf][c][tk-chunks^] 64KB
    __shared__ unsigned short Plds[8][16 * TS];       // per-wave [qr][tk-chunks^]  8KB
    __shared__ float mlm[64], mll[64];

    int tid = threadIdx.x;
    int b  = blockIdx.y;
    int Q0 = blockIdx.x * 64;
    int lane = tid & 63;
    int w = tid >> 6;
    int lw = w & 3;        // wave's Q-row block
    int g2 = w >> 2;       // KV half
    int g = lane >> 4, l15 = lane & 15;
    int tg = tid & 255;    // thread index within group

    // Q fragments hoisted to registers (32 VGPR)
    bf16x8 qf[8];
    {
        const unsigned short* qp = q + ((size_t)b * N + Q0 + lw * 16 + l15) * C + g * 8;
#pragma unroll
        for (int kc = 0; kc < 8; ++kc)
            qf[kc] = *(const bf16x8*)(qp + kc * 32);
    }

    f32x4 oacc[16];
#pragma unroll
    for (int i = 0; i < 16; ++i) oacc[i] = f32x4{0.f, 0.f, 0.f, 0.f};
    float mrow[4], lrow[4];
#pragma unroll
    for (int r = 0; r < 4; ++r) { mrow[r] = -1e30f; lrow[r] = 0.f; }

    const unsigned short* kb = kt + ((size_t)b * N + g2 * 2048) * C;
    const unsigned short* vb = v + (size_t)b * C * N + g2 * 2048;

    // ---- staging: per thread 4 K-chunks + 4 V-chunks of 16B, LDS linear ----
    // K: q=tg+j*256: tk=q>>5, slot=q&31 holds global chunk slot^(tk&7)
    // V: q=tg+j*256: c=q>>2,  slot=q&3  holds global chunk slot^((c>>1)&3)
#define STAGE(buf_, t_)                                                              \
    {                                                                                \
        const unsigned short* kbt = kb + (size_t)(t_) * TS * 256;                    \
        _Pragma("unroll")                                                            \
        for (int j = 0; j < 4; ++j) {                                                \
            int qq = tg + j * 256;                                                   \
            int tk = qq >> 5, sc = qq & 31;                                          \
            stage16(kbt + tk * 256 + ((sc ^ (tk & 7)) * 8), &Klds[g2][buf_][qq * 8]);\
        }                                                                            \
        _Pragma("unroll")                                                            \
        for (int j = 0; j < 4; ++j) {                                                \
            int qq = tg + j * 256;                                                   \
            int c = qq >> 2, sl = qq & 3;                                            \
            stage16(vb + (size_t)c * N + (t_) * TS + ((sl ^ ((c >> 1) & 3)) * 8),    \
                    &Vlds[g2][buf_][qq * 8]);                                        \
        }                                                                            \
    }

    STAGE(0, 0);
    __syncthreads();   // drains vmcnt: tile 0 ready

    for (int t = 0; t < 64; ++t) {
        int cur = t & 1;
        if (t < 63) STAGE(cur ^ 1, t + 1);   // issue next tile; hides under compute

        // S = Q K^T  (2 col-tiles x 8 K-steps)
        f32x4 s[2];
#pragma unroll
        for (int ct = 0; ct < 2; ++ct) s[ct] = f32x4{0.f, 0.f, 0.f, 0.f};
#pragma unroll
        for (int kc = 0; kc < 8; ++kc) {
#pragma unroll
            for (int ct = 0; ct < 2; ++ct) {
                int tk = ct * 16 + l15;
                int slot = (kc * 4 + g) ^ (tk & 7);
                bf16x8 kf = *(const bf16x8*)&Klds[g2][cur][tk * 256 + slot * 8];
                s[ct] = __builtin_amdgcn_mfma_f32_16x16x32_bf16(qf[kc], kf, s[ct], 0, 0, 0);
            }
        }

        // online softmax (all 64 lanes active)
        float alpha[4];
#pragma unroll
        for (int r = 0; r < 4; ++r) {
            float mx = fmaxf(s[0][r], s[1][r]);
            for (int off = 1; off < 16; off <<= 1) mx = fmaxf(mx, __shfl_xor(mx, off));
            float mn = fmaxf(mrow[r], mx);
            alpha[r] = __expf(mrow[r] - mn);
            mrow[r] = mn;
            float p0 = __expf(s[0][r] - mn);
            float p1 = __expf(s[1][r] - mn);
            s[0][r] = p0; s[1][r] = p1;
            float rs = p0 + p1;
            for (int off = 1; off < 16; off <<= 1) rs += __shfl_xor(rs, off);
            lrow[r] = lrow[r] * alpha[r] + rs;
        }
        bool nochg = (alpha[0] == 1.f) & (alpha[1] == 1.f) & (alpha[2] == 1.f) & (alpha[3] == 1.f);
        if (!__all(nochg)) {
#pragma unroll
            for (int f = 0; f < 16; ++f)
#pragma unroll
                for (int r = 0; r < 4; ++r) oacc[f][r] *= alpha[r];
        }

        // P -> per-wave LDS (bf16, swizzled same XOR family as V)
#pragma unroll
        for (int ct = 0; ct < 2; ++ct) {
#pragma unroll
            for (int r = 0; r < 4; ++r) {
                int row = g * 4 + r;
                int lc = ct * 2 + (l15 >> 3);
                int slot = lc ^ ((row >> 1) & 3);
                Plds[w][row * TS + slot * 8 + (l15 & 7)] = f2bf(s[ct][r]);
            }
        }

        // O += P V  (one MFMA per 16-col tile; K-dim = TS = 32)
        {
            int pslot = g ^ ((l15 >> 1) & 3);
            bf16x8 pf = *(const bf16x8*)&Plds[w][l15 * TS + pslot * 8];
#pragma unroll
            for (int cf = 0; cf < 16; ++cf) {
                int c = cf * 16 + l15;
                int vslot = g ^ ((c >> 1) & 3);
                bf16x8 vf = *(const bf16x8*)&Vlds[g2][cur][c * TS + vslot * 8];
                oacc[cf] = __builtin_amdgcn_mfma_f32_16x16x32_bf16(pf, vf, oacc[cf], 0, 0, 0);
            }
        }
        __syncthreads();   // drains vmcnt: tile t+1 ready, buf cur free for t+2
    }

    // ---- epilogue: combine the two KV halves via LDS (reuse Klds as fp32 buffer) ----
    float* Ocomb = (float*)&Klds[0][0][0];   // 64 rows x 256 c fp32 = 64KB
    if (g2 == 1) {
#pragma unroll
        for (int cf = 0; cf < 16; ++cf)
#pragma unroll
            for (int r = 0; r < 4; ++r)
                Ocomb[(size_t)(lw * 16 + g * 4 + r) * 256 + cf * 16 + l15] = oacc[cf][r];
        if (l15 == 0) {
#pragma unroll
            for (int r = 0; r < 4; ++r) {
                int row = lw * 16 + g * 4 + r;
                mlm[row] = mrow[r];
                mll[row] = lrow[r];
            }
        }
    }
    __syncthreads();
    if (g2 == 0) {
        float w0[4], w1[4];
#pragma unroll
        for (int r = 0; r < 4; ++r) {
            int row = lw * 16 + g * 4 + r;
            float m1 = mlm[row], l1 = mll[row];
            float m = fmaxf(mrow[r], m1);
            float a0 = __expf(mrow[r] - m), a1 = __expf(m1 - m);
            float inv = 1.f / (a0 * lrow[r] + a1 * l1);
            w0[r] = a0 * inv;
            w1[r] = a1 * inv;
        }
#pragma unroll
        for (int cf = 0; cf < 16; ++cf) {
            int c = cf * 16 + l15;
#pragma unroll
            for (int r = 0; r < 4; ++r) {
                int row = lw * 16 + g * 4 + r;
                float val = w0[r] * oacc[cf][r] + w1[r] * Ocomb[(size_t)row * 256 + c];
                ao[((size_t)b * N + Q0 + row) * C + c] = f2bf(val);
            }
        }
    }
}

// ---------------- Kernel 4: out projection + bias + residual ----------------
__global__ __launch_bounds__(256) void out_gemm_k(
    const unsigned short* __restrict__ ao, const float* __restrict__ Wout,
    const float* __restrict__ bout, const float* __restrict__ x, float* __restrict__ out)
{
    __shared__ unsigned short Alds[64 * 72];
    __shared__ unsigned short Blds[128 * 72];
    int tid = threadIdx.x;
    int b   = blockIdx.z;
    int CO0 = blockIdx.y * 64;
    int T0  = blockIdx.x * 128;
    int lane = tid & 63;
    int w = tid >> 6;
    int wm = w >> 1, wn = w & 1;
    int g = lane >> 4, l15 = lane & 15;

    f32x4 acc[2][4];
    for (int i = 0; i < 2; ++i)
        for (int j = 0; j < 4; ++j) acc[i][j] = f32x4{0.f, 0.f, 0.f, 0.f};

    int a_r = tid >> 2;
    int a_cb = (tid & 3) * 16;

    for (int c0 = 0; c0 < C; c0 += 64) {
        {
            const float4* wp = (const float4*)(Wout + (size_t)(CO0 + a_r) * C + c0 + a_cb);
            for (int j = 0; j < 4; ++j) {
                float4 vv = wp[j];
                int base = a_r * 72 + a_cb + j * 4;
                Alds[base + 0] = f2bf(vv.x);
                Alds[base + 1] = f2bf(vv.y);
                Alds[base + 2] = f2bf(vv.z);
                Alds[base + 3] = f2bf(vv.w);
            }
        }
        for (int it = 0; it < 4; ++it) {
            int chunk = tid + it * 256;
            int tl = chunk >> 3, j = chunk & 7;
            *(bf16x8*)&Blds[tl * 72 + j * 8] =
                *(const bf16x8*)(ao + ((size_t)b * N + T0 + tl) * C + c0 + j * 8);
        }
        __syncthreads();
        for (int kk = 0; kk < 2; ++kk) {
            bf16x8 bfr[4];
            for (int nf = 0; nf < 4; ++nf)
                bfr[nf] = *(const bf16x8*)&Blds[(wn * 64 + nf * 16 + l15) * 72 + kk * 32 + g * 8];
            for (int mf = 0; mf < 2; ++mf) {
                bf16x8 afr = *(const bf16x8*)&Alds[(wm * 32 + mf * 16 + l15) * 72 + kk * 32 + g * 8];
                for (int nf = 0; nf < 4; ++nf)
                    acc[mf][nf] = __builtin_amdgcn_mfma_f32_16x16x32_bf16(afr, bfr[nf], acc[mf][nf], 0, 0, 0);
            }
        }
        __syncthreads();
    }
    for (int mf = 0; mf < 2; ++mf) {
        for (int nf = 0; nf < 4; ++nf) {
            int t = T0 + wn * 64 + nf * 16 + l15;
            for (int r = 0; r < 4; ++r) {
                int co = CO0 + wm * 32 + mf * 16 + g * 4 + r;
                size_t oidx = ((size_t)b * C + co) * N + t;
                out[oidx] = acc[mf][nf][r] + bout[co] + x[oidx];
            }
        }
    }
}

extern "C" void kernel_launch(void* const* d_in, const int* in_sizes, int n_in,
                              void* d_out, int out_size, void* d_ws, size_t ws_size,
                              hipStream_t stream) {
    const float* x     = (const float*)d_in[0];
    const float* Wqkv  = (const float*)d_in[1];
    const float* bqkv  = (const float*)d_in[2];
    const float* Wout  = (const float*)d_in[3];
    const float* bout  = (const float*)d_in[4];
    const float* gamma = (const float*)d_in[5];
    const float* beta  = (const float*)d_in[6];
    float* out = (float*)d_out;

    char* ws = (char*)d_ws;
    float* scale = (float*)ws;
    float* shift = (float*)(ws + 1024);
    unsigned short* q  = (unsigned short*)(ws + 4096);
    unsigned short* kt = q  + (size_t)BB * N * C;
    unsigned short* v  = kt + (size_t)BB * N * C;
    unsigned short* ao = v  + (size_t)BB * N * C;

    bn_stats_k<<<dim3(C), dim3(256), 0, stream>>>(x, gamma, beta, scale, shift);
    qkv_gemm_k<<<dim3(12, 32, BB), dim3(256), 0, stream>>>(x, Wqkv, bqkv, scale, shift, q, kt, v);
    attn_k<<<dim3(64, BB), dim3(512), 0, stream>>>(q, kt, v, ao);
    out_gemm_k<<<dim3(32, 4, BB), dim3(256), 0, stream>>>(ao, Wout, bout, x, out);
}